// Round 10
// baseline (320.803 us; speedup 1.0000x reference)
//
#include <hip/hip_runtime.h>
#include <hip/hip_bf16.h>

// ---------------------------------------------------------------------------
// GraphChebNet: 3-layer ChebConv (K=2), N=50000, E=400000.
// Round 18: resubmission of round-14..17 (four GPU-capacity failures in a
// row; still unmeasured). GEMM 2-phase double-buffered pipeline. rocprof r13:
// gemm_mfma K=256 = 46 µs, MfmaUtil 9.7%, VALU 6.3%, HBM 21% -> latency-bound
// on the stage->drain->MFMA serialization (8 steps x 40KB staging, full load
// latency exposed each step). As/Bs double-buffered (80KB LDS, 2 blocks/CU):
// STAGE(t+1) issues before compute(t), one __syncthreads per step drains the
// prefetch AFTER MFMA has covered its latency (catalog T3-minimum recipe,
// setprio(1) around MFMA). Barriers/step 2->1. Everything else = round 13
// (atomic-free fill via rank capture; split gather/GEMM — fusion was -66 µs).
// ---------------------------------------------------------------------------

typedef __attribute__((ext_vector_type(8))) short bf16x8;
typedef __attribute__((ext_vector_type(4))) float f32x4;

__device__ __forceinline__ float bf2f(unsigned int lo16) {
    unsigned int t = lo16 << 16;
    return __builtin_bit_cast(float, t);
}
__device__ __forceinline__ unsigned short f2bf(float f) {
    unsigned int u = __builtin_bit_cast(unsigned int, f);
    unsigned int r = (u + 0x7fffu + ((u >> 16) & 1u)) >> 16;   // RNE
    return (unsigned short)r;
}

// ---------------- fused prep: deg/cnt histograms + cast x + transpose W ----
struct PrepParams {
    const int* src;
    const int* dst;
    int* deg;        // int histogram of non-self out-edges (by src)
    int* cnt;        // int histogram of in-edges (by dst)
    int* rank;       // rank[e] = arrival rank of edge e within its dst row
    int E;
    const float* x;
    unsigned short* xb;
    int gE;     // blocks for edge histogram
    int gC;     // blocks for x cast
    const float* W[6];
    unsigned short* WT[6];
    int K[6];
};

__global__ __launch_bounds__(256) void prep_kernel(PrepParams p) {
    __shared__ float t[32][33];
    int b = blockIdx.x;
    int tid = threadIdx.x;
    if (b < p.gE) {
        int e = b * 256 + tid;
        if (e < p.E) {
            int s = p.src[e], d = p.dst[e];
            if (s != d) atomicAdd(&p.deg[s], 1);
            p.rank[e] = atomicAdd(&p.cnt[d], 1);   // rank piggybacks on histogram
        }
        return;
    }
    b -= p.gE;
    if (b < p.gC) {
        long long i = (long long)b * 256 + tid;   // n4 elements exactly = gC*256
        float4 v = reinterpret_cast<const float4*>(p.x)[i];
        ushort4 o;
        o.x = f2bf(v.x); o.y = f2bf(v.y); o.z = f2bf(v.z); o.w = f2bf(v.w);
        reinterpret_cast<ushort4*>(p.xb)[i] = o;
        return;
    }
    b -= p.gC;                       // 0..383 : 6 matrices x 64 tiles
    int m = b >> 6;
    int rem = b & 63;
    int K = p.K[m];
    int kb = (rem & 7) * 32, nb = (rem >> 3) * 32;
    if (kb >= K) return;
    const float* W = p.W[m];
    unsigned short* WT = p.WT[m];
    int lx = tid & 31, ly = tid >> 5;   // 32 x 8
    #pragma unroll
    for (int i = 0; i < 32; i += 8)
        t[ly + i][lx] = W[(size_t)(kb + ly + i) * 256 + nb + lx];
    __syncthreads();
    #pragma unroll
    for (int i = 0; i < 32; i += 8)
        WT[(size_t)(nb + ly + i) * K + kb + lx] = f2bf(t[lx][ly + i]);
}

// ---------------- scan: partial sums + dinv (int deg -> float rsqrt) -------
__global__ __launch_bounds__(256) void scan_partial_dinv(const int* __restrict__ cnt,
                                                         int* __restrict__ part,
                                                         int* __restrict__ deg, int N) {
    __shared__ int lds[256];
    int tid = threadIdx.x;
    int base = blockIdx.x * 1024 + tid * 4;
    int s = 0;
    #pragma unroll
    for (int i = 0; i < 4; ++i) {
        if (base + i < N) {
            s += cnt[base + i];
            int d = deg[base + i];
            float dv = (d > 0) ? rsqrtf((float)d) : 0.0f;
            reinterpret_cast<float*>(deg)[base + i] = dv;   // deg -> dinv in place
        }
    }
    lds[tid] = s;
    __syncthreads();
    for (int off = 128; off > 0; off >>= 1) {
        if (tid < off) lds[tid] += lds[tid + off];
        __syncthreads();
    }
    if (tid == 0) part[blockIdx.x] = lds[0];
}

// chunk scan; each block redundantly wave-scans the (<=64) raw partials to get
// its own exclusive offset (scan_small dispatch eliminated).
__global__ __launch_bounds__(256) void scan_chunk(const int* __restrict__ cnt,
                                                  const int* __restrict__ part,
                                                  int* __restrict__ rowptr, int N, int NB) {
    __shared__ int lds[256];
    __shared__ int blockOff;
    int tid = threadIdx.x;
    if (tid < 64) {
        int v = (tid < NB) ? part[tid] : 0;
        int inc = v;
        #pragma unroll
        for (int off = 1; off < 64; off <<= 1) {
            int t = __shfl_up(inc, off, 64);
            if (tid >= off) inc += t;
        }
        if (tid == (int)blockIdx.x) blockOff = inc - v;           // exclusive
        if (blockIdx.x == 0 && tid == NB - 1) rowptr[N] = inc;    // total
    }
    __syncthreads();
    int base = blockIdx.x * 1024 + tid * 4;
    int c[4];
    #pragma unroll
    for (int i = 0; i < 4; ++i) c[i] = (base + i < N) ? cnt[base + i] : 0;
    int ts = c[0] + c[1] + c[2] + c[3];
    lds[tid] = ts;
    __syncthreads();
    for (int off = 1; off < 256; off <<= 1) {
        int v = (tid >= off) ? lds[tid - off] : 0;
        __syncthreads();
        lds[tid] += v;
        __syncthreads();
    }
    int o = blockOff + lds[tid] - ts;
    #pragma unroll
    for (int i = 0; i < 4; ++i) {
        if (base + i < N) rowptr[base + i] = o;
        o += c[i];
    }
}

// CSR fill, atomic-free: pos = rowptr[d] + rank[e] (rank captured in prep).
// Edge record packed as int2 {src, bits(weight)}: one 8B load per edge later.
__global__ __launch_bounds__(256) void fill_kernel(const int* __restrict__ src,
                                                   const int* __restrict__ dst,
                                                   const int* __restrict__ rank,
                                                   const float* __restrict__ dinv,
                                                   const int* __restrict__ rowptr,
                                                   int2* __restrict__ epk, int E) {
    int e = blockIdx.x * blockDim.x + threadIdx.x;
    if (e < E) {
        int s = src[e], d = dst[e];
        int pos = rowptr[d] + rank[e];
        float w = (s != d) ? (-dinv[s] * dinv[d]) : 0.0f;
        epk[pos] = make_int2(s, __builtin_bit_cast(int, w));
    }
}

// ---------------- gather: tx[n,:] = sum_e w_e * x[src_e,:] ----------------
// half-wave (32 lanes) per node; lane holds V=F/32 bf16 features; edge loop
// unrolled x8 (avg degree 8) -> 8 independent row loads in flight.
template <int V> struct RowT;
template <> struct RowT<4> { using T = uint2; };
template <> struct RowT<8> { using T = uint4; };

__device__ __forceinline__ void fma_row(float* acc, uint2 u, float wv) {
    acc[0] += wv * bf2f(u.x & 0xffffu);
    acc[1] += wv * bf2f(u.x >> 16);
    acc[2] += wv * bf2f(u.y & 0xffffu);
    acc[3] += wv * bf2f(u.y >> 16);
}
__device__ __forceinline__ void fma_row(float* acc, uint4 u, float wv) {
    acc[0] += wv * bf2f(u.x & 0xffffu);
    acc[1] += wv * bf2f(u.x >> 16);
    acc[2] += wv * bf2f(u.y & 0xffffu);
    acc[3] += wv * bf2f(u.y >> 16);
    acc[4] += wv * bf2f(u.z & 0xffffu);
    acc[5] += wv * bf2f(u.z >> 16);
    acc[6] += wv * bf2f(u.w & 0xffffu);
    acc[7] += wv * bf2f(u.w >> 16);
}
__device__ __forceinline__ void pack_out(unsigned short* q, const float* acc, uint2*) {
    uint2 o;
    o.x = (unsigned int)f2bf(acc[0]) | ((unsigned int)f2bf(acc[1]) << 16);
    o.y = (unsigned int)f2bf(acc[2]) | ((unsigned int)f2bf(acc[3]) << 16);
    *reinterpret_cast<uint2*>(q) = o;
}
__device__ __forceinline__ void pack_out(unsigned short* q, const float* acc, uint4*) {
    uint4 o;
    o.x = (unsigned int)f2bf(acc[0]) | ((unsigned int)f2bf(acc[1]) << 16);
    o.y = (unsigned int)f2bf(acc[2]) | ((unsigned int)f2bf(acc[3]) << 16);
    o.z = (unsigned int)f2bf(acc[4]) | ((unsigned int)f2bf(acc[5]) << 16);
    o.w = (unsigned int)f2bf(acc[6]) | ((unsigned int)f2bf(acc[7]) << 16);
    *reinterpret_cast<uint4*>(q) = o;
}

template <int F>
__global__ __launch_bounds__(256) void gather_bf16(const int* __restrict__ rowptr,
                                                   const int2* __restrict__ epk,
                                                   const unsigned short* __restrict__ xb,
                                                   unsigned short* __restrict__ txb,
                                                   int N) {
    constexpr int V = F / 32;   // 4 (F=128) or 8 (F=256)
    using T = typename RowT<V>::T;
    int half = threadIdx.x >> 5;     // 0..7
    int lane = threadIdx.x & 31;
    int n = blockIdx.x * 8 + half;
    if (n >= N) return;
    int beg = rowptr[n], end = rowptr[n + 1];
    float acc[V] = {};

    int k = beg;
    for (; k + 8 <= end; k += 8) {
        int2 ep[8]; T r[8];
        #pragma unroll
        for (int j = 0; j < 8; ++j) ep[j] = epk[k + j];
        #pragma unroll
        for (int j = 0; j < 8; ++j)
            r[j] = *reinterpret_cast<const T*>(&xb[(size_t)ep[j].x * F + lane * V]);
        #pragma unroll
        for (int j = 0; j < 8; ++j)
            fma_row(acc, r[j], __builtin_bit_cast(float, ep[j].y));
    }
    for (; k + 4 <= end; k += 4) {
        int2 e0 = epk[k], e1 = epk[k + 1], e2 = epk[k + 2], e3 = epk[k + 3];
        T r0 = *reinterpret_cast<const T*>(&xb[(size_t)e0.x * F + lane * V]);
        T r1 = *reinterpret_cast<const T*>(&xb[(size_t)e1.x * F + lane * V]);
        T r2 = *reinterpret_cast<const T*>(&xb[(size_t)e2.x * F + lane * V]);
        T r3 = *reinterpret_cast<const T*>(&xb[(size_t)e3.x * F + lane * V]);
        fma_row(acc, r0, __builtin_bit_cast(float, e0.y));
        fma_row(acc, r1, __builtin_bit_cast(float, e1.y));
        fma_row(acc, r2, __builtin_bit_cast(float, e2.y));
        fma_row(acc, r3, __builtin_bit_cast(float, e3.y));
    }
    for (; k < end; ++k) {
        int2 e = epk[k];
        T r = *reinterpret_cast<const T*>(&xb[(size_t)e.x * F + lane * V]);
        fma_row(acc, r, __builtin_bit_cast(float, e.y));
    }

    pack_out(&txb[(size_t)n * F + lane * V], acc, (T*)nullptr);
}

// ---------------- MFMA GEMM, 2-phase double-buffered pipeline --------------
// out[M,256] = relu?( Xb[M,K]@W0 + Tb[M,K]@W1 + b ), weights as WT[n][k] bf16.
// LDS rows are 64 shorts (128B, no pad). Source columns XOR-swizzled in 16B
// units: LDS unit u of row R holds global unit u^(R&7); reader fetches unit
// g at LDS unit g^(l15&7) -> 2-way bank aliasing only (free).
// Pipeline: STAGE(t+1 -> buf^1) issued BEFORE compute(t); single __syncthreads
// per step drains the prefetch after MFMA covered its latency (T3-minimum).
template <int K, bool RELU, typename OutT>
__global__ __launch_bounds__(256, 2) void gemm_mfma(const unsigned short* __restrict__ Xb,
                                                    const unsigned short* __restrict__ Tb,
                                                    const unsigned short* __restrict__ W0T,
                                                    const unsigned short* __restrict__ W1T,
                                                    const float* __restrict__ bias,
                                                    OutT* __restrict__ out, int M) {
    constexpr int KSTEPS = K / 64;
    constexpr int NT = 2 * KSTEPS;
    __shared__ unsigned short As[2][64 * 64];     // 2 x 8KB
    __shared__ unsigned short Bs[2][256 * 64];    // 2 x 32KB

    const int tid = threadIdx.x;
    const int wave = tid >> 6;
    const int lane = tid & 63;
    const int l15 = lane & 15;
    const int quad = lane >> 4;
    const int row0 = blockIdx.x * 64;
    // staging: lane l of wave w covers row (base + w*8 + (l>>3)), 16B unit (l&7),
    // swizzled source unit = (l&7) ^ ((l>>3)&7)  [row&7 == (l>>3)&7]
    const int swz = ((lane & 7) ^ ((lane >> 3) & 7)) * 8;   // shorts

    f32x4 acc[4][4];
    #pragma unroll
    for (int i = 0; i < 4; ++i)
        #pragma unroll
        for (int j = 0; j < 4; ++j) acc[i][j] = (f32x4){0.f, 0.f, 0.f, 0.f};

    typedef const __attribute__((address_space(1))) void gvoid;
    typedef __attribute__((address_space(3))) void lvoid;

    auto stage = [&](int t, int buf) {
        const unsigned short* Amat = (t < KSTEPS) ? Xb : Tb;
        const unsigned short* Wmat = (t < KSTEPS) ? W0T : W1T;
        const int k0 = (t & (KSTEPS - 1)) * 64;
        #pragma unroll
        for (int r = 0; r < 2; ++r) {
            int grow = row0 + r * 32 + wave * 8 + (lane >> 3);
            if (grow > M - 1) grow = M - 1;
            const unsigned short* gp = &Amat[(size_t)grow * K + k0 + swz];
            __builtin_amdgcn_global_load_lds((gvoid*)gp,
                (lvoid*)&As[buf][(r * 32 + wave * 8) * 64], 16, 0, 0);
        }
        #pragma unroll
        for (int r = 0; r < 8; ++r) {
            int brow = r * 32 + wave * 8 + (lane >> 3);
            const unsigned short* gp = &Wmat[(size_t)brow * K + k0 + swz];
            __builtin_amdgcn_global_load_lds((gvoid*)gp,
                (lvoid*)&Bs[buf][(r * 32 + wave * 8) * 64], 16, 0, 0);
        }
    };

    stage(0, 0);
    __syncthreads();                 // prologue drain (vmcnt0 + barrier)

    int cur = 0;
    for (int t = 0; t < NT; ++t) {
        if (t + 1 < NT) stage(t + 1, cur ^ 1);   // prefetch next tile
        #pragma unroll
        for (int kf = 0; kf < 2; ++kf) {
            const int col = (((kf * 4 + quad) ^ (l15 & 7)) * 8);
            bf16x8 a[4], b[4];
            #pragma unroll
            for (int mt = 0; mt < 4; ++mt)
                a[mt] = *reinterpret_cast<const bf16x8*>(&As[cur][(mt * 16 + l15) * 64 + col]);
            #pragma unroll
            for (int nt = 0; nt < 4; ++nt)
                b[nt] = *reinterpret_cast<const bf16x8*>(
                    &Bs[cur][(wave * 64 + nt * 16 + l15) * 64 + col]);
            __builtin_amdgcn_s_setprio(1);
            #pragma unroll
            for (int mt = 0; mt < 4; ++mt)
                #pragma unroll
                for (int nt = 0; nt < 4; ++nt)
                    acc[mt][nt] = __builtin_amdgcn_mfma_f32_16x16x32_bf16(
                        a[mt], b[nt], acc[mt][nt], 0, 0, 0);
            __builtin_amdgcn_s_setprio(0);
        }
        __syncthreads();             // drains prefetch; all waves done with cur
        cur ^= 1;
    }

    // epilogue: C/D layout col=lane&15, row=quad*4+reg
    #pragma unroll
    for (int mt = 0; mt < 4; ++mt) {
        #pragma unroll
        for (int r = 0; r < 4; ++r) {
            int m = row0 + mt * 16 + quad * 4 + r;
            if (m >= M) continue;
            #pragma unroll
            for (int nt = 0; nt < 4; ++nt) {
                int n = wave * 64 + nt * 16 + l15;
                float v = acc[mt][nt][r] + bias[n];
                if (RELU) v = fmaxf(v, 0.0f);
                if constexpr (sizeof(OutT) == 2)
                    out[(size_t)m * 256 + n] = (OutT)f2bf(v);
                else
                    out[(size_t)m * 256 + n] = (OutT)v;
            }
        }
    }
}

static inline size_t align_up(size_t v, size_t a) { return (v + a - 1) / a * a; }

extern "C" void kernel_launch(void* const* d_in, const int* in_sizes, int n_in,
                              void* d_out, int out_size, void* d_ws, size_t ws_size,
                              hipStream_t stream) {
    const float* x    = (const float*)d_in[0];
    const int*   ei   = (const int*)d_in[1];
    const float* W1_0 = (const float*)d_in[2];
    const float* W1_1 = (const float*)d_in[3];
    const float* b1   = (const float*)d_in[4];
    const float* W2_0 = (const float*)d_in[5];
    const float* W2_1 = (const float*)d_in[6];
    const float* b2   = (const float*)d_in[7];
    const float* W3_0 = (const float*)d_in[8];
    const float* W3_1 = (const float*)d_in[9];
    const float* b3   = (const float*)d_in[10];
    float* out = (float*)d_out;

    const int N = in_sizes[0] / 128;
    const int E = in_sizes[1] / 2;
    const int* src = ei;
    const int* dst = ei + E;

    typedef unsigned short u16;
    char* ws = (char*)d_ws;
    size_t off = 0;
    int*   deg    = (int*)  (ws + off); off = align_up(off + (size_t)N * 4, 256);  // -> dinv
    int*   cnt    = (int*)  (ws + off); off = align_up(off + (size_t)N * 4, 256);
    size_t zero_end = off;                     // one memset covers deg+cnt
    int*   rank   = (int*)  (ws + off); off = align_up(off + (size_t)E * 4, 256);
    int*   rowptr = (int*)  (ws + off); off = align_up(off + (size_t)(N + 1) * 4, 256);
    int*   part   = (int*)  (ws + off); off = align_up(off + 256 * 4, 256);
    int2*  epk    = (int2*) (ws + off); off = align_up(off + (size_t)E * 8, 256);
    u16*   xb     = (u16*)  (ws + off); off = align_up(off + (size_t)N * 128 * 2, 256);
    u16*   txb    = (u16*)  (ws + off); off = align_up(off + (size_t)N * 256 * 2, 256);
    u16*   h1b    = (u16*)  (ws + off); off = align_up(off + (size_t)N * 256 * 2, 256);
    u16*   h2b    = (u16*)  (ws + off); off = align_up(off + (size_t)N * 256 * 2, 256);
    u16*   W10T   = (u16*)  (ws + off); off = align_up(off + (size_t)256 * 128 * 2, 256);
    u16*   W11T   = (u16*)  (ws + off); off = align_up(off + (size_t)256 * 128 * 2, 256);
    u16*   W20T   = (u16*)  (ws + off); off = align_up(off + (size_t)256 * 256 * 2, 256);
    u16*   W21T   = (u16*)  (ws + off); off = align_up(off + (size_t)256 * 256 * 2, 256);
    u16*   W30T   = (u16*)  (ws + off); off = align_up(off + (size_t)256 * 256 * 2, 256);
    u16*   W31T   = (u16*)  (ws + off); off = align_up(off + (size_t)256 * 256 * 2, 256);
    (void)ws_size;

    const int TB = 256;
    const int gE = (E + TB - 1) / TB;                       // 1563
    const int gC = (int)(((long long)N * 128 / 4) / 256);   // 6250 (exact)
    const int NB = (N + 1023) / 1024;                       // 49 (<= 64 required)

    // ---- init ----
    hipMemsetAsync(deg, 0, zero_end, stream);

    // ---- fused prep: histograms(+rank) + cast x + transpose weights ----
    {
        PrepParams p;
        p.src = src; p.dst = dst; p.deg = deg; p.cnt = cnt; p.rank = rank; p.E = E;
        p.x = x; p.xb = xb; p.gE = gE; p.gC = gC;
        p.W[0] = W1_0; p.WT[0] = W10T; p.K[0] = 128;
        p.W[1] = W1_1; p.WT[1] = W11T; p.K[1] = 128;
        p.W[2] = W2_0; p.WT[2] = W20T; p.K[2] = 256;
        p.W[3] = W2_1; p.WT[3] = W21T; p.K[3] = 256;
        p.W[4] = W3_0; p.WT[4] = W30T; p.K[4] = 256;
        p.W[5] = W3_1; p.WT[5] = W31T; p.K[5] = 256;
        prep_kernel<<<gE + gC + 384, TB, 0, stream>>>(p);
    }

    // ---- CSR build (deg->dinv conversion inside scan_partial) ----
    scan_partial_dinv<<<NB, 256, 0, stream>>>(cnt, part, deg, N);
    scan_chunk<<<NB, 256, 0, stream>>>(cnt, part, rowptr, N, NB);
    fill_kernel<<<(E + TB - 1) / TB, TB, 0, stream>>>(src, dst, rank,
                                                      (const float*)deg, rowptr, epk, E);

    dim3 gemmGrid((N + 63) / 64);
    dim3 gatherGrid((N + 7) / 8);

    // ---- layer 1: F=128 ----
    gather_bf16<128><<<gatherGrid, TB, 0, stream>>>(rowptr, epk, xb, txb, N);
    gemm_mfma<128, true, u16><<<gemmGrid, TB, 0, stream>>>(xb, txb, W10T, W11T, b1, h1b, N);

    // ---- layer 2: F=256 ----
    gather_bf16<256><<<gatherGrid, TB, 0, stream>>>(rowptr, epk, h1b, txb, N);
    gemm_mfma<256, true, u16><<<gemmGrid, TB, 0, stream>>>(h1b, txb, W20T, W21T, b2, h2b, N);

    // ---- layer 3: F=256, no relu, fp32 out ----
    gather_bf16<256><<<gatherGrid, TB, 0, stream>>>(rowptr, epk, h2b, txb, N);
    gemm_mfma<256, false, float><<<gemmGrid, TB, 0, stream>>>(h2b, txb, W30T, W31T, b3, out, N);
}

// Round 11
// 304.086 us; speedup vs baseline: 1.0550x; 1.0550x over previous
//
#include <hip/hip_runtime.h>
#include <hip/hip_bf16.h>

// ---------------------------------------------------------------------------
// GraphChebNet: 3-layer ChebConv (K=2), N=50000, E=400000.
// Round 19: GEMM BM 64->128. r18 measured the double-buffer NEUTRAL (total
// 320.8 vs 315.1 with prep +10% session noise) -> barrier-drain floor is
// independent of buffering at 32 MFMA/step. Fix: double work per staged byte:
// 128-row tile, 64 MFMA/wave/step vs 40->48KB staging, half the blocks ->
// half the B L2 traffic. Single-buffer (dbuf neutral), 2 barriers/step,
// launch_bounds(256,2) for acc[8][4] (~180 VGPR). gemm: 285 TF-equiv -> pred
// ~2x. Everything else = r13/r18 (atomic-free fill, packed epk, split phases).
// ---------------------------------------------------------------------------

typedef __attribute__((ext_vector_type(8))) short bf16x8;
typedef __attribute__((ext_vector_type(4))) float f32x4;

__device__ __forceinline__ float bf2f(unsigned int lo16) {
    unsigned int t = lo16 << 16;
    return __builtin_bit_cast(float, t);
}
__device__ __forceinline__ unsigned short f2bf(float f) {
    unsigned int u = __builtin_bit_cast(unsigned int, f);
    unsigned int r = (u + 0x7fffu + ((u >> 16) & 1u)) >> 16;   // RNE
    return (unsigned short)r;
}

// ---------------- fused prep: deg/cnt histograms + cast x + transpose W ----
struct PrepParams {
    const int* src;
    const int* dst;
    int* deg;        // int histogram of non-self out-edges (by src)
    int* cnt;        // int histogram of in-edges (by dst)
    int* rank;       // rank[e] = arrival rank of edge e within its dst row
    int E;
    const float* x;
    unsigned short* xb;
    int gE;     // blocks for edge histogram
    int gC;     // blocks for x cast
    const float* W[6];
    unsigned short* WT[6];
    int K[6];
};

__global__ __launch_bounds__(256) void prep_kernel(PrepParams p) {
    __shared__ float t[32][33];
    int b = blockIdx.x;
    int tid = threadIdx.x;
    if (b < p.gE) {
        int e = b * 256 + tid;
        if (e < p.E) {
            int s = p.src[e], d = p.dst[e];
            if (s != d) atomicAdd(&p.deg[s], 1);
            p.rank[e] = atomicAdd(&p.cnt[d], 1);   // rank piggybacks on histogram
        }
        return;
    }
    b -= p.gE;
    if (b < p.gC) {
        long long i = (long long)b * 256 + tid;   // n4 elements exactly = gC*256
        float4 v = reinterpret_cast<const float4*>(p.x)[i];
        ushort4 o;
        o.x = f2bf(v.x); o.y = f2bf(v.y); o.z = f2bf(v.z); o.w = f2bf(v.w);
        reinterpret_cast<ushort4*>(p.xb)[i] = o;
        return;
    }
    b -= p.gC;                       // 0..383 : 6 matrices x 64 tiles
    int m = b >> 6;
    int rem = b & 63;
    int K = p.K[m];
    int kb = (rem & 7) * 32, nb = (rem >> 3) * 32;
    if (kb >= K) return;
    const float* W = p.W[m];
    unsigned short* WT = p.WT[m];
    int lx = tid & 31, ly = tid >> 5;   // 32 x 8
    #pragma unroll
    for (int i = 0; i < 32; i += 8)
        t[ly + i][lx] = W[(size_t)(kb + ly + i) * 256 + nb + lx];
    __syncthreads();
    #pragma unroll
    for (int i = 0; i < 32; i += 8)
        WT[(size_t)(nb + ly + i) * K + kb + lx] = f2bf(t[lx][ly + i]);
}

// ---------------- scan: partial sums + dinv (int deg -> float rsqrt) -------
__global__ __launch_bounds__(256) void scan_partial_dinv(const int* __restrict__ cnt,
                                                         int* __restrict__ part,
                                                         int* __restrict__ deg, int N) {
    __shared__ int lds[256];
    int tid = threadIdx.x;
    int base = blockIdx.x * 1024 + tid * 4;
    int s = 0;
    #pragma unroll
    for (int i = 0; i < 4; ++i) {
        if (base + i < N) {
            s += cnt[base + i];
            int d = deg[base + i];
            float dv = (d > 0) ? rsqrtf((float)d) : 0.0f;
            reinterpret_cast<float*>(deg)[base + i] = dv;   // deg -> dinv in place
        }
    }
    lds[tid] = s;
    __syncthreads();
    for (int off = 128; off > 0; off >>= 1) {
        if (tid < off) lds[tid] += lds[tid + off];
        __syncthreads();
    }
    if (tid == 0) part[blockIdx.x] = lds[0];
}

// chunk scan; each block redundantly wave-scans the (<=64) raw partials to get
// its own exclusive offset (scan_small dispatch eliminated).
__global__ __launch_bounds__(256) void scan_chunk(const int* __restrict__ cnt,
                                                  const int* __restrict__ part,
                                                  int* __restrict__ rowptr, int N, int NB) {
    __shared__ int lds[256];
    __shared__ int blockOff;
    int tid = threadIdx.x;
    if (tid < 64) {
        int v = (tid < NB) ? part[tid] : 0;
        int inc = v;
        #pragma unroll
        for (int off = 1; off < 64; off <<= 1) {
            int t = __shfl_up(inc, off, 64);
            if (tid >= off) inc += t;
        }
        if (tid == (int)blockIdx.x) blockOff = inc - v;           // exclusive
        if (blockIdx.x == 0 && tid == NB - 1) rowptr[N] = inc;    // total
    }
    __syncthreads();
    int base = blockIdx.x * 1024 + tid * 4;
    int c[4];
    #pragma unroll
    for (int i = 0; i < 4; ++i) c[i] = (base + i < N) ? cnt[base + i] : 0;
    int ts = c[0] + c[1] + c[2] + c[3];
    lds[tid] = ts;
    __syncthreads();
    for (int off = 1; off < 256; off <<= 1) {
        int v = (tid >= off) ? lds[tid - off] : 0;
        __syncthreads();
        lds[tid] += v;
        __syncthreads();
    }
    int o = blockOff + lds[tid] - ts;
    #pragma unroll
    for (int i = 0; i < 4; ++i) {
        if (base + i < N) rowptr[base + i] = o;
        o += c[i];
    }
}

// CSR fill, atomic-free: pos = rowptr[d] + rank[e] (rank captured in prep).
// Edge record packed as int2 {src, bits(weight)}: one 8B load per edge later.
__global__ __launch_bounds__(256) void fill_kernel(const int* __restrict__ src,
                                                   const int* __restrict__ dst,
                                                   const int* __restrict__ rank,
                                                   const float* __restrict__ dinv,
                                                   const int* __restrict__ rowptr,
                                                   int2* __restrict__ epk, int E) {
    int e = blockIdx.x * blockDim.x + threadIdx.x;
    if (e < E) {
        int s = src[e], d = dst[e];
        int pos = rowptr[d] + rank[e];
        float w = (s != d) ? (-dinv[s] * dinv[d]) : 0.0f;
        epk[pos] = make_int2(s, __builtin_bit_cast(int, w));
    }
}

// ---------------- gather: tx[n,:] = sum_e w_e * x[src_e,:] ----------------
// half-wave (32 lanes) per node; lane holds V=F/32 bf16 features; edge loop
// unrolled x8 (avg degree 8) -> 8 independent row loads in flight.
template <int V> struct RowT;
template <> struct RowT<4> { using T = uint2; };
template <> struct RowT<8> { using T = uint4; };

__device__ __forceinline__ void fma_row(float* acc, uint2 u, float wv) {
    acc[0] += wv * bf2f(u.x & 0xffffu);
    acc[1] += wv * bf2f(u.x >> 16);
    acc[2] += wv * bf2f(u.y & 0xffffu);
    acc[3] += wv * bf2f(u.y >> 16);
}
__device__ __forceinline__ void fma_row(float* acc, uint4 u, float wv) {
    acc[0] += wv * bf2f(u.x & 0xffffu);
    acc[1] += wv * bf2f(u.x >> 16);
    acc[2] += wv * bf2f(u.y & 0xffffu);
    acc[3] += wv * bf2f(u.y >> 16);
    acc[4] += wv * bf2f(u.z & 0xffffu);
    acc[5] += wv * bf2f(u.z >> 16);
    acc[6] += wv * bf2f(u.w & 0xffffu);
    acc[7] += wv * bf2f(u.w >> 16);
}
__device__ __forceinline__ void pack_out(unsigned short* q, const float* acc, uint2*) {
    uint2 o;
    o.x = (unsigned int)f2bf(acc[0]) | ((unsigned int)f2bf(acc[1]) << 16);
    o.y = (unsigned int)f2bf(acc[2]) | ((unsigned int)f2bf(acc[3]) << 16);
    *reinterpret_cast<uint2*>(q) = o;
}
__device__ __forceinline__ void pack_out(unsigned short* q, const float* acc, uint4*) {
    uint4 o;
    o.x = (unsigned int)f2bf(acc[0]) | ((unsigned int)f2bf(acc[1]) << 16);
    o.y = (unsigned int)f2bf(acc[2]) | ((unsigned int)f2bf(acc[3]) << 16);
    o.z = (unsigned int)f2bf(acc[4]) | ((unsigned int)f2bf(acc[5]) << 16);
    o.w = (unsigned int)f2bf(acc[6]) | ((unsigned int)f2bf(acc[7]) << 16);
    *reinterpret_cast<uint4*>(q) = o;
}

template <int F>
__global__ __launch_bounds__(256) void gather_bf16(const int* __restrict__ rowptr,
                                                   const int2* __restrict__ epk,
                                                   const unsigned short* __restrict__ xb,
                                                   unsigned short* __restrict__ txb,
                                                   int N) {
    constexpr int V = F / 32;   // 4 (F=128) or 8 (F=256)
    using T = typename RowT<V>::T;
    int half = threadIdx.x >> 5;     // 0..7
    int lane = threadIdx.x & 31;
    int n = blockIdx.x * 8 + half;
    if (n >= N) return;
    int beg = rowptr[n], end = rowptr[n + 1];
    float acc[V] = {};

    int k = beg;
    for (; k + 8 <= end; k += 8) {
        int2 ep[8]; T r[8];
        #pragma unroll
        for (int j = 0; j < 8; ++j) ep[j] = epk[k + j];
        #pragma unroll
        for (int j = 0; j < 8; ++j)
            r[j] = *reinterpret_cast<const T*>(&xb[(size_t)ep[j].x * F + lane * V]);
        #pragma unroll
        for (int j = 0; j < 8; ++j)
            fma_row(acc, r[j], __builtin_bit_cast(float, ep[j].y));
    }
    for (; k + 4 <= end; k += 4) {
        int2 e0 = epk[k], e1 = epk[k + 1], e2 = epk[k + 2], e3 = epk[k + 3];
        T r0 = *reinterpret_cast<const T*>(&xb[(size_t)e0.x * F + lane * V]);
        T r1 = *reinterpret_cast<const T*>(&xb[(size_t)e1.x * F + lane * V]);
        T r2 = *reinterpret_cast<const T*>(&xb[(size_t)e2.x * F + lane * V]);
        T r3 = *reinterpret_cast<const T*>(&xb[(size_t)e3.x * F + lane * V]);
        fma_row(acc, r0, __builtin_bit_cast(float, e0.y));
        fma_row(acc, r1, __builtin_bit_cast(float, e1.y));
        fma_row(acc, r2, __builtin_bit_cast(float, e2.y));
        fma_row(acc, r3, __builtin_bit_cast(float, e3.y));
    }
    for (; k < end; ++k) {
        int2 e = epk[k];
        T r = *reinterpret_cast<const T*>(&xb[(size_t)e.x * F + lane * V]);
        fma_row(acc, r, __builtin_bit_cast(float, e.y));
    }

    pack_out(&txb[(size_t)n * F + lane * V], acc, (T*)nullptr);
}

// ---------------- MFMA GEMM, BM=128, single-buffer ------------------------
// out[M,256] = relu?( Xb[M,K]@W0 + Tb[M,K]@W1 + b ), weights as WT[n][k] bf16.
// 128-row tile: 64 MFMA/wave per K-step against 48KB staging (2x the work per
// staged byte of the 64-row tile; half the blocks -> half the B L2 traffic).
// LDS rows are 64 shorts (128B, no pad). Source columns XOR-swizzled in 16B
// units: LDS unit u of row R holds global unit u^(R&7); reader fetches unit
// g at LDS unit g^(l15&7) -> 2-way bank aliasing only (free).
template <int K, bool RELU, typename OutT>
__global__ __launch_bounds__(256, 2) void gemm_mfma(const unsigned short* __restrict__ Xb,
                                                    const unsigned short* __restrict__ Tb,
                                                    const unsigned short* __restrict__ W0T,
                                                    const unsigned short* __restrict__ W1T,
                                                    const float* __restrict__ bias,
                                                    OutT* __restrict__ out, int M) {
    __shared__ unsigned short As[128 * 64];   // 16KB
    __shared__ unsigned short Bs[256 * 64];   // 32KB

    const int tid = threadIdx.x;
    const int wave = tid >> 6;
    const int lane = tid & 63;
    const int l15 = lane & 15;
    const int quad = lane >> 4;
    const int row0 = blockIdx.x * 128;
    // staging: lane l of wave w covers row (base + w*8 + (l>>3)), 16B unit (l&7),
    // swizzled source unit = (l&7) ^ ((l>>3)&7)  [row&7 == (l>>3)&7]
    const int swz = ((lane & 7) ^ ((lane >> 3) & 7)) * 8;   // shorts

    f32x4 acc[8][4];
    #pragma unroll
    for (int i = 0; i < 8; ++i)
        #pragma unroll
        for (int j = 0; j < 4; ++j) acc[i][j] = (f32x4){0.f, 0.f, 0.f, 0.f};

    typedef const __attribute__((address_space(1))) void gvoid;
    typedef __attribute__((address_space(3))) void lvoid;

    #pragma unroll
    for (int pass = 0; pass < 2; ++pass) {
        const unsigned short* Amat = pass ? Tb : Xb;
        const unsigned short* Wmat = pass ? W1T : W0T;
        for (int k0 = 0; k0 < K; k0 += 64) {
            if (pass != 0 || k0 != 0) __syncthreads();
            #pragma unroll
            for (int r = 0; r < 4; ++r) {
                int grow = row0 + r * 32 + wave * 8 + (lane >> 3);
                if (grow > M - 1) grow = M - 1;
                const unsigned short* gp = &Amat[(size_t)grow * K + k0 + swz];
                __builtin_amdgcn_global_load_lds((gvoid*)gp,
                    (lvoid*)&As[(r * 32 + wave * 8) * 64], 16, 0, 0);
            }
            #pragma unroll
            for (int r = 0; r < 8; ++r) {
                int brow = r * 32 + wave * 8 + (lane >> 3);
                const unsigned short* gp = &Wmat[(size_t)brow * K + k0 + swz];
                __builtin_amdgcn_global_load_lds((gvoid*)gp,
                    (lvoid*)&Bs[(r * 32 + wave * 8) * 64], 16, 0, 0);
            }
            __syncthreads();

            #pragma unroll
            for (int kf = 0; kf < 2; ++kf) {
                const int col = (((kf * 4 + quad) ^ (l15 & 7)) * 8);
                bf16x8 b[4];
                #pragma unroll
                for (int nt = 0; nt < 4; ++nt)
                    b[nt] = *reinterpret_cast<const bf16x8*>(
                        &Bs[(wave * 64 + nt * 16 + l15) * 64 + col]);
                #pragma unroll
                for (int mt = 0; mt < 8; ++mt) {
                    bf16x8 a = *reinterpret_cast<const bf16x8*>(
                        &As[(mt * 16 + l15) * 64 + col]);
                    #pragma unroll
                    for (int nt = 0; nt < 4; ++nt)
                        acc[mt][nt] = __builtin_amdgcn_mfma_f32_16x16x32_bf16(
                            a, b[nt], acc[mt][nt], 0, 0, 0);
                }
            }
        }
    }

    // epilogue: C/D layout col=lane&15, row=quad*4+reg
    #pragma unroll
    for (int mt = 0; mt < 8; ++mt) {
        #pragma unroll
        for (int r = 0; r < 4; ++r) {
            int m = row0 + mt * 16 + quad * 4 + r;
            if (m >= M) continue;
            #pragma unroll
            for (int nt = 0; nt < 4; ++nt) {
                int n = wave * 64 + nt * 16 + l15;
                float v = acc[mt][nt][r] + bias[n];
                if (RELU) v = fmaxf(v, 0.0f);
                if constexpr (sizeof(OutT) == 2)
                    out[(size_t)m * 256 + n] = (OutT)f2bf(v);
                else
                    out[(size_t)m * 256 + n] = (OutT)v;
            }
        }
    }
}

static inline size_t align_up(size_t v, size_t a) { return (v + a - 1) / a * a; }

extern "C" void kernel_launch(void* const* d_in, const int* in_sizes, int n_in,
                              void* d_out, int out_size, void* d_ws, size_t ws_size,
                              hipStream_t stream) {
    const float* x    = (const float*)d_in[0];
    const int*   ei   = (const int*)d_in[1];
    const float* W1_0 = (const float*)d_in[2];
    const float* W1_1 = (const float*)d_in[3];
    const float* b1   = (const float*)d_in[4];
    const float* W2_0 = (const float*)d_in[5];
    const float* W2_1 = (const float*)d_in[6];
    const float* b2   = (const float*)d_in[7];
    const float* W3_0 = (const float*)d_in[8];
    const float* W3_1 = (const float*)d_in[9];
    const float* b3   = (const float*)d_in[10];
    float* out = (float*)d_out;

    const int N = in_sizes[0] / 128;
    const int E = in_sizes[1] / 2;
    const int* src = ei;
    const int* dst = ei + E;

    typedef unsigned short u16;
    char* ws = (char*)d_ws;
    size_t off = 0;
    int*   deg    = (int*)  (ws + off); off = align_up(off + (size_t)N * 4, 256);  // -> dinv
    int*   cnt    = (int*)  (ws + off); off = align_up(off + (size_t)N * 4, 256);
    size_t zero_end = off;                     // one memset covers deg+cnt
    int*   rank   = (int*)  (ws + off); off = align_up(off + (size_t)E * 4, 256);
    int*   rowptr = (int*)  (ws + off); off = align_up(off + (size_t)(N + 1) * 4, 256);
    int*   part   = (int*)  (ws + off); off = align_up(off + 256 * 4, 256);
    int2*  epk    = (int2*) (ws + off); off = align_up(off + (size_t)E * 8, 256);
    u16*   xb     = (u16*)  (ws + off); off = align_up(off + (size_t)N * 128 * 2, 256);
    u16*   txb    = (u16*)  (ws + off); off = align_up(off + (size_t)N * 256 * 2, 256);
    u16*   h1b    = (u16*)  (ws + off); off = align_up(off + (size_t)N * 256 * 2, 256);
    u16*   h2b    = (u16*)  (ws + off); off = align_up(off + (size_t)N * 256 * 2, 256);
    u16*   W10T   = (u16*)  (ws + off); off = align_up(off + (size_t)256 * 128 * 2, 256);
    u16*   W11T   = (u16*)  (ws + off); off = align_up(off + (size_t)256 * 128 * 2, 256);
    u16*   W20T   = (u16*)  (ws + off); off = align_up(off + (size_t)256 * 256 * 2, 256);
    u16*   W21T   = (u16*)  (ws + off); off = align_up(off + (size_t)256 * 256 * 2, 256);
    u16*   W30T   = (u16*)  (ws + off); off = align_up(off + (size_t)256 * 256 * 2, 256);
    u16*   W31T   = (u16*)  (ws + off); off = align_up(off + (size_t)256 * 256 * 2, 256);
    (void)ws_size;

    const int TB = 256;
    const int gE = (E + TB - 1) / TB;                       // 1563
    const int gC = (int)(((long long)N * 128 / 4) / 256);   // 6250 (exact)
    const int NB = (N + 1023) / 1024;                       // 49 (<= 64 required)

    // ---- init ----
    hipMemsetAsync(deg, 0, zero_end, stream);

    // ---- fused prep: histograms(+rank) + cast x + transpose weights ----
    {
        PrepParams p;
        p.src = src; p.dst = dst; p.deg = deg; p.cnt = cnt; p.rank = rank; p.E = E;
        p.x = x; p.xb = xb; p.gE = gE; p.gC = gC;
        p.W[0] = W1_0; p.WT[0] = W10T; p.K[0] = 128;
        p.W[1] = W1_1; p.WT[1] = W11T; p.K[1] = 128;
        p.W[2] = W2_0; p.WT[2] = W20T; p.K[2] = 256;
        p.W[3] = W2_1; p.WT[3] = W21T; p.K[3] = 256;
        p.W[4] = W3_0; p.WT[4] = W30T; p.K[4] = 256;
        p.W[5] = W3_1; p.WT[5] = W31T; p.K[5] = 256;
        prep_kernel<<<gE + gC + 384, TB, 0, stream>>>(p);
    }

    // ---- CSR build (deg->dinv conversion inside scan_partial) ----
    scan_partial_dinv<<<NB, 256, 0, stream>>>(cnt, part, deg, N);
    scan_chunk<<<NB, 256, 0, stream>>>(cnt, part, rowptr, N, NB);
    fill_kernel<<<(E + TB - 1) / TB, TB, 0, stream>>>(src, dst, rank,
                                                      (const float*)deg, rowptr, epk, E);

    dim3 gemmGrid((N + 127) / 128);
    dim3 gatherGrid((N + 7) / 8);

    // ---- layer 1: F=128 ----
    gather_bf16<128><<<gatherGrid, TB, 0, stream>>>(rowptr, epk, xb, txb, N);
    gemm_mfma<128, true, u16><<<gemmGrid, TB, 0, stream>>>(xb, txb, W10T, W11T, b1, h1b, N);

    // ---- layer 2: F=256 ----
    gather_bf16<256><<<gatherGrid, TB, 0, stream>>>(rowptr, epk, h1b, txb, N);
    gemm_mfma<256, true, u16><<<gemmGrid, TB, 0, stream>>>(h1b, txb, W20T, W21T, b2, h2b, N);

    // ---- layer 3: F=256, no relu, fp32 out ----
    gather_bf16<256><<<gatherGrid, TB, 0, stream>>>(rowptr, epk, h2b, txb, N);
    gemm_mfma<256, false, float><<<gemmGrid, TB, 0, stream>>>(h2b, txb, W30T, W31T, b3, out, N);
}